// Round 1
// baseline (1617.548 us; speedup 1.0000x reference)
//
#include <hip/hip_runtime.h>
#include <hip/hip_bf16.h>

// AdditiveAttention restructured:
//   kk[b]  = keys[b] @ W_k                      [50,1024]   (f32)
//   Mb[b]  = (1/32) * W_o^T @ kk[b]             [512,1024]  (f32)
//   N[b]   = Mb[b] @ W_q^T                      [512,1024]  (bf16)
//   logits[b,v,q] = sum_i N[b,v,i]*queries[b,q,i]           (f32, = scores2)
//   attn   = softmax(mask(logits)) over q axis   -> d_out[1]
//   T[b]   = attn[b] @ values[b]                [512,1024]  (bf16)
//   out[b] = T[b] @ W_v                         [512,1024]  (f32) -> d_out[0]

#define NB   32
#define LQ   2048
#define LK   50
#define DIN  1024
#define DHID 1024
#define DVAL 512

typedef short bf16x8 __attribute__((ext_vector_type(8)));
typedef float f32x4  __attribute__((ext_vector_type(4)));
typedef unsigned short u16x8 __attribute__((ext_vector_type(8)));

static __device__ __forceinline__ unsigned short f2b(float f) {
  __hip_bfloat16 h = __float2bfloat16(f);
  unsigned short u;
  __builtin_memcpy(&u, &h, 2);
  return u;
}

// ---------------- kproj: kk[row,h] = sum_i keys[row,i] * W_k[i,h] ----------
// grid 100 blocks x 256 thr; block handles 16 rows x 1024 h (4 h per thread)
__global__ __launch_bounds__(256) void kproj_kernel(
    const float* __restrict__ keys, const float* __restrict__ W_k,
    float* __restrict__ kk) {
  __shared__ float ks_[16][64];
  const int t  = threadIdx.x;
  const int r0 = blockIdx.x * 16;
  float4 acc[16];
#pragma unroll
  for (int r = 0; r < 16; ++r) acc[r] = make_float4(0.f, 0.f, 0.f, 0.f);

  for (int i0 = 0; i0 < DIN; i0 += 64) {
    __syncthreads();
    {
      const int rr = t >> 4, cc = (t & 15) * 4;
      *reinterpret_cast<float4*>(&ks_[rr][cc]) =
          *reinterpret_cast<const float4*>(keys + (long)(r0 + rr) * DIN + i0 + cc);
    }
    __syncthreads();
    for (int ii = 0; ii < 64; ++ii) {
      const float4 w = *reinterpret_cast<const float4*>(W_k + (long)(i0 + ii) * DHID + t * 4);
#pragma unroll
      for (int r = 0; r < 16; ++r) {
        const float kv = ks_[r][ii];
        acc[r].x += kv * w.x; acc[r].y += kv * w.y;
        acc[r].z += kv * w.z; acc[r].w += kv * w.w;
      }
    }
  }
#pragma unroll
  for (int r = 0; r < 16; ++r)
    *reinterpret_cast<float4*>(kk + (long)(r0 + r) * DHID + t * 4) = acc[r];
}

// ---------------- Mb[b,v,h] = (1/32) sum_k W_o[k,v]*kk[b*50+k,h] -----------
// grid B*V blocks x 256 thr; 4 h per thread
__global__ __launch_bounds__(256) void mb_kernel(
    const float* __restrict__ kk, const float* __restrict__ W_o,
    float* __restrict__ Mb) {
  const int bv = blockIdx.x;
  const int b = bv >> 9, v = bv & 511;
  const int t = threadIdx.x;
  const float* kb = kk + (long)b * LK * DHID + t * 4;
  float ax = 0.f, ay = 0.f, az = 0.f, aw = 0.f;
  for (int k = 0; k < LK; ++k) {
    const float wo = W_o[k * DVAL + v];
    const float4 kv = *reinterpret_cast<const float4*>(kb + (long)k * DHID);
    ax += wo * kv.x; ay += wo * kv.y; az += wo * kv.z; aw += wo * kv.w;
  }
  float4 r;
  r.x = ax * 0.03125f; r.y = ay * 0.03125f; r.z = az * 0.03125f; r.w = aw * 0.03125f;
  *reinterpret_cast<float4*>(Mb + (long)bv * DHID + t * 4) = r;
}

// ---------------- batched bf16 MFMA GEMM -----------------------------------
// C[m,n] = sum_k A[m,k] * B'[n,k]
//   BTRANS=true : B stored [N,K] row-major (B'[n,k] = B[n*ldb+k])
//   BTRANS=false: B stored [K,N] row-major (B'[n,k] = B[k*ldb+n]); f32 only
#define BM 128
#define BN 128
#define BK 64
#define LDSK 72  // +8 bf16 pad: keeps 16B alignment, breaks bank stride

template <typename AT, typename BT, typename OT, bool BTRANS>
__global__ __launch_bounds__(256, 2) void gemm_kernel(
    const AT* __restrict__ Ag, const BT* __restrict__ Bg, OT* __restrict__ Cg,
    int K, int lda, int ldb, int ldc, long strideA, long strideB, long strideC) {
  __shared__ unsigned short As[BM * LDSK];
  __shared__ unsigned short Bs[BN * LDSK];

  const int tid = threadIdx.x;
  Ag += (long)blockIdx.z * strideA;
  Bg += (long)blockIdx.z * strideB;
  Cg += (long)blockIdx.z * strideC;
  const int m0 = blockIdx.y * BM;
  const int n0 = blockIdx.x * BN;

  const int w    = tid >> 6;
  const int lane = tid & 63;
  const int l15  = lane & 15;
  const int quad = lane >> 4;
  const int wm   = (w >> 1) * 64;
  const int wn   = (w & 1) * 64;

  f32x4 acc[4][4];
#pragma unroll
  for (int i = 0; i < 4; ++i)
#pragma unroll
    for (int j = 0; j < 4; ++j) acc[i][j] = (f32x4)(0.0f);

  const int arow = tid >> 1;        // 128 rows, 2 threads/row
  const int aseg = (tid & 1) * 32;  // 32 elements each
  const int bkrow = tid >> 2;       // NN: 64 k-rows, 4 threads/row
  const int bnn0  = (tid & 3) * 32; // NN: 32 n-cols each

  for (int k0 = 0; k0 < K; k0 += BK) {
    // ---- stage A tile (rows m0.., cols k0..k0+63) -> As[m][k]
    {
      unsigned short* dst = &As[arow * LDSK + aseg];
      if constexpr (sizeof(AT) == 4) {
        const float4* src = reinterpret_cast<const float4*>(
            reinterpret_cast<const float*>(Ag) + (long)(m0 + arow) * lda + k0 + aseg);
#pragma unroll
        for (int u = 0; u < 4; ++u) {
          const float4 f0 = src[2 * u + 0];
          const float4 f1 = src[2 * u + 1];
          u16x8 p;
          p[0] = f2b(f0.x); p[1] = f2b(f0.y); p[2] = f2b(f0.z); p[3] = f2b(f0.w);
          p[4] = f2b(f1.x); p[5] = f2b(f1.y); p[6] = f2b(f1.z); p[7] = f2b(f1.w);
          *reinterpret_cast<u16x8*>(dst + u * 8) = p;
        }
      } else {
        const float4* src = reinterpret_cast<const float4*>(
            reinterpret_cast<const unsigned short*>(Ag) + (long)(m0 + arow) * lda + k0 + aseg);
#pragma unroll
        for (int u = 0; u < 4; ++u)
          reinterpret_cast<float4*>(dst)[u] = src[u];
      }
    }
    // ---- stage B tile -> Bs[n][k]
    if constexpr (BTRANS) {
      unsigned short* dst = &Bs[arow * LDSK + aseg];
      if constexpr (sizeof(BT) == 4) {
        const float4* src = reinterpret_cast<const float4*>(
            reinterpret_cast<const float*>(Bg) + (long)(n0 + arow) * ldb + k0 + aseg);
#pragma unroll
        for (int u = 0; u < 4; ++u) {
          const float4 f0 = src[2 * u + 0];
          const float4 f1 = src[2 * u + 1];
          u16x8 p;
          p[0] = f2b(f0.x); p[1] = f2b(f0.y); p[2] = f2b(f0.z); p[3] = f2b(f0.w);
          p[4] = f2b(f1.x); p[5] = f2b(f1.y); p[6] = f2b(f1.z); p[7] = f2b(f1.w);
          *reinterpret_cast<u16x8*>(dst + u * 8) = p;
        }
      } else {
        const float4* src = reinterpret_cast<const float4*>(
            reinterpret_cast<const unsigned short*>(Bg) + (long)(n0 + arow) * ldb + k0 + aseg);
#pragma unroll
        for (int u = 0; u < 4; ++u)
          reinterpret_cast<float4*>(dst)[u] = src[u];
      }
    } else {
      if constexpr (sizeof(BT) == 4) {  // only f32 NN sources exist here
        const float4* src = reinterpret_cast<const float4*>(
            reinterpret_cast<const float*>(Bg) + (long)(k0 + bkrow) * ldb + n0 + bnn0);
#pragma unroll
        for (int u = 0; u < 8; ++u) {
          const float4 f = src[u];
          const int nn = bnn0 + u * 4;
          Bs[(nn + 0) * LDSK + bkrow] = f2b(f.x);
          Bs[(nn + 1) * LDSK + bkrow] = f2b(f.y);
          Bs[(nn + 2) * LDSK + bkrow] = f2b(f.z);
          Bs[(nn + 3) * LDSK + bkrow] = f2b(f.w);
        }
      }
    }
    __syncthreads();

#pragma unroll
    for (int ks = 0; ks < BK; ks += 32) {
      bf16x8 af[4], bfv[4];
#pragma unroll
      for (int i = 0; i < 4; ++i)
        af[i] = *reinterpret_cast<const bf16x8*>(&As[(wm + i * 16 + l15) * LDSK + ks + quad * 8]);
#pragma unroll
      for (int j = 0; j < 4; ++j)
        bfv[j] = *reinterpret_cast<const bf16x8*>(&Bs[(wn + j * 16 + l15) * LDSK + ks + quad * 8]);
#pragma unroll
      for (int i = 0; i < 4; ++i)
#pragma unroll
        for (int j = 0; j < 4; ++j)
          acc[i][j] = __builtin_amdgcn_mfma_f32_16x16x32_bf16(af[i], bfv[j], acc[i][j], 0, 0, 0);
    }
    __syncthreads();
  }

  // epilogue: D row = wm+i*16+quad*4+r, col = wn+j*16+l15
#pragma unroll
  for (int i = 0; i < 4; ++i) {
#pragma unroll
    for (int j = 0; j < 4; ++j) {
#pragma unroll
      for (int r = 0; r < 4; ++r) {
        const int row = m0 + wm + i * 16 + quad * 4 + r;
        const int col = n0 + wn + j * 16 + l15;
        const float val = acc[i][j][r];
        if constexpr (sizeof(OT) == 2) {
          reinterpret_cast<__hip_bfloat16*>(Cg)[(long)row * ldc + col] = __float2bfloat16(val);
        } else {
          reinterpret_cast<float*>(Cg)[(long)row * ldc + col] = val;
        }
      }
    }
  }
}

// ---------------- masked softmax over q (in-place on [B*V][2048]) ----------
__global__ __launch_bounds__(256) void softmax_kernel(
    float* __restrict__ attn, const int* __restrict__ vlens) {
  __shared__ float smax[4], ssum[4];
  const long base = (long)blockIdx.x * LQ;
  const int vl = vlens[blockIdx.x >> 9];
  const int t = threadIdx.x;
  float x[8];
  float mx = -3.0e38f;
#pragma unroll
  for (int u = 0; u < 8; ++u) {
    const int q = u * 256 + t;
    float v = attn[base + q];
    if (q >= vl) v = -1000000.0f;
    x[u] = v;
    mx = fmaxf(mx, v);
  }
#pragma unroll
  for (int off = 32; off > 0; off >>= 1) mx = fmaxf(mx, __shfl_down(mx, off));
  if ((t & 63) == 0) smax[t >> 6] = mx;
  __syncthreads();
  mx = fmaxf(fmaxf(smax[0], smax[1]), fmaxf(smax[2], smax[3]));
  float s = 0.f;
#pragma unroll
  for (int u = 0; u < 8; ++u) { x[u] = __expf(x[u] - mx); s += x[u]; }
#pragma unroll
  for (int off = 32; off > 0; off >>= 1) s += __shfl_down(s, off);
  if ((t & 63) == 0) ssum[t >> 6] = s;
  __syncthreads();
  s = ssum[0] + ssum[1] + ssum[2] + ssum[3];
  const float inv = 1.0f / s;
#pragma unroll
  for (int u = 0; u < 8; ++u) attn[base + u * 256 + t] = x[u] * inv;
}

extern "C" void kernel_launch(void* const* d_in, const int* in_sizes, int n_in,
                              void* d_out, int out_size, void* d_ws, size_t ws_size,
                              hipStream_t stream) {
  const float* queries = (const float*)d_in[0];
  const float* keys    = (const float*)d_in[1];
  const float* values  = (const float*)d_in[2];
  const int*   vlens   = (const int*)d_in[3];
  const float* W_q     = (const float*)d_in[4];
  const float* W_k     = (const float*)d_in[5];
  const float* W_v     = (const float*)d_in[6];
  const float* W_o     = (const float*)d_in[7];

  float* out  = (float*)d_out;                       // [32][512][1024]
  float* attn = out + (size_t)NB * DVAL * DHID;      // [32][512][2048]

  char* ws = (char*)d_ws;
  float* kk = (float*)ws;                                     //  6.55 MB
  float* Mb = (float*)(ws + (size_t)LK * NB * DHID * 4);      // 67.1 MB
  __hip_bfloat16* Nb = (__hip_bfloat16*)(ws + 6553600UL + 67108864UL);   // 33.6 MB
  __hip_bfloat16* Tb = (__hip_bfloat16*)(ws + 6553600UL + 67108864UL + 33554432UL); // 33.6 MB

  kproj_kernel<<<dim3(100), 256, 0, stream>>>(keys, W_k, kk);
  mb_kernel<<<dim3(NB * DVAL), 256, 0, stream>>>(kk, W_o, Mb);

  // N[b] = Mb[b] @ W_q^T : M=512,N=1024,K=1024 (Bt = W_q [i][h])
  gemm_kernel<float, float, __hip_bfloat16, true><<<dim3(8, 4, NB), 256, 0, stream>>>(
      Mb, W_q, Nb, 1024, 1024, 1024, 1024, (long)512 * 1024, 0, (long)512 * 1024);

  // logits[b] = N[b] @ queries[b]^T : M=512,N=2048,K=1024 -> d_out attn region
  gemm_kernel<__hip_bfloat16, float, float, true><<<dim3(16, 4, NB), 256, 0, stream>>>(
      Nb, queries, attn, 1024, 1024, 1024, 2048, (long)512 * 1024, (long)2048 * 1024,
      (long)512 * 2048);

  softmax_kernel<<<dim3(NB * DVAL), 256, 0, stream>>>(attn, vlens);

  // T[b] = attn[b] @ values[b] : M=512,N=1024,K=2048 (NN)
  gemm_kernel<float, float, __hip_bfloat16, false><<<dim3(8, 4, NB), 256, 0, stream>>>(
      attn, values, Tb, 2048, 2048, 1024, 1024, (long)512 * 2048, (long)2048 * 1024,
      (long)512 * 1024);

  // out[b] = T[b] @ W_v : M=512,N=1024,K=1024 (NN, shared B)
  gemm_kernel<__hip_bfloat16, float, float, false><<<dim3(8, 4, NB), 256, 0, stream>>>(
      Tb, W_v, out, 1024, 1024, 1024, 1024, (long)512 * 1024, 0, (long)512 * 1024);
}

// Round 2
// 1376.674 us; speedup vs baseline: 1.1750x; 1.1750x over previous
//
#include <hip/hip_runtime.h>
#include <hip/hip_bf16.h>

// AdditiveAttention restructured (all GEMMs bf16 MFMA, BTRANS layout):
//   qb   = bf16(queries)                        [B,2048,1024]
//   kk   = keys @ W_k                           [B,50,1024]   (f32)
//   Mb   = bf16((1/32) * W_o^T @ kk)            [B,512,1024]
//   N    = Mb @ W_q^T                           [B,512,1024]  (bf16)
//   logits[b,v,q] = sum_i N[b,v,i]*qb[b,q,i]    -> d_out attn region (f32)
//   vT   = bf16(values^T)                       [B,1024,2048]
//   attn = softmax(mask(logits))                f32 -> d_out; bf16 -> attnb
//   T    = attnb @ vT^T(=values)                [B,512,1024]  (bf16)
//   out  = T @ wvT^T(=W_v)                      [B,512,1024]  (f32) -> d_out

#define NB   32
#define LQ   2048
#define LK   50
#define DIN  1024
#define DHID 1024
#define DVAL 512

typedef short bf16x8 __attribute__((ext_vector_type(8)));
typedef float f32x4  __attribute__((ext_vector_type(4)));
typedef unsigned short u16x8 __attribute__((ext_vector_type(8)));
typedef unsigned short u16x4 __attribute__((ext_vector_type(4)));

static __device__ __forceinline__ unsigned short f2b(float f) {
  __hip_bfloat16 h = __float2bfloat16(f);
  unsigned short u;
  __builtin_memcpy(&u, &h, 2);
  return u;
}

// ---------------- f32 -> bf16 elementwise (n multiple of 2048) -------------
__global__ __launch_bounds__(256) void cvt_bf16_kernel(
    const float* __restrict__ in, unsigned short* __restrict__ outp, long n) {
  const long i = ((long)blockIdx.x * 256 + threadIdx.x) * 8;
  if (i >= n) return;
  const float4 a = *reinterpret_cast<const float4*>(in + i);
  const float4 b = *reinterpret_cast<const float4*>(in + i + 4);
  u16x8 p;
  p[0] = f2b(a.x); p[1] = f2b(a.y); p[2] = f2b(a.z); p[3] = f2b(a.w);
  p[4] = f2b(b.x); p[5] = f2b(b.y); p[6] = f2b(b.z); p[7] = f2b(b.w);
  *reinterpret_cast<u16x8*>(outp + i) = p;
}

// ---------------- transpose + convert: in f32 [R,C] -> out bf16 [C,R] ------
__global__ __launch_bounds__(256) void transpose_bf16_kernel(
    const float* __restrict__ in, unsigned short* __restrict__ outp,
    int R, int C, long sIn, long sOut) {
  __shared__ float t[64][65];
  in   += (long)blockIdx.z * sIn;
  outp += (long)blockIdx.z * sOut;
  const int r0 = blockIdx.y * 64, c0 = blockIdx.x * 64;
  const int tid = threadIdx.x;
  const int lr = tid >> 4;          // 0..15
  const int lc = (tid & 15) * 4;    // 0..60
#pragma unroll
  for (int u = 0; u < 4; ++u) {
    const float4 v = *reinterpret_cast<const float4*>(
        in + (long)(r0 + lr + u * 16) * C + c0 + lc);
    t[lc + 0][lr + u * 16] = v.x; t[lc + 1][lr + u * 16] = v.y;
    t[lc + 2][lr + u * 16] = v.z; t[lc + 3][lr + u * 16] = v.w;
  }
  __syncthreads();
  const int orow = tid >> 2;        // 0..63 (output row, = input col)
  const int oseg = (tid & 3) * 16;  // 16 elements
  u16x8 p0, p1;
#pragma unroll
  for (int u = 0; u < 8; ++u) p0[u] = f2b(t[orow][oseg + u]);
#pragma unroll
  for (int u = 0; u < 8; ++u) p1[u] = f2b(t[orow][oseg + 8 + u]);
  unsigned short* o = outp + (long)(c0 + orow) * R + r0 + oseg;
  *reinterpret_cast<u16x8*>(o)     = p0;
  *reinterpret_cast<u16x8*>(o + 8) = p1;
}

// ---------------- kproj: kk[row,h] = sum_i keys[row,i] * W_k[i,h] ----------
__global__ __launch_bounds__(256) void kproj_kernel(
    const float* __restrict__ keys, const float* __restrict__ W_k,
    float* __restrict__ kk) {
  __shared__ float ks_[16][64];
  const int t  = threadIdx.x;
  const int r0 = blockIdx.x * 16;
  float4 acc[16];
#pragma unroll
  for (int r = 0; r < 16; ++r) acc[r] = make_float4(0.f, 0.f, 0.f, 0.f);

  for (int i0 = 0; i0 < DIN; i0 += 64) {
    __syncthreads();
    {
      const int rr = t >> 4, cc = (t & 15) * 4;
      *reinterpret_cast<float4*>(&ks_[rr][cc]) =
          *reinterpret_cast<const float4*>(keys + (long)(r0 + rr) * DIN + i0 + cc);
    }
    __syncthreads();
    for (int ii = 0; ii < 64; ++ii) {
      const float4 w = *reinterpret_cast<const float4*>(W_k + (long)(i0 + ii) * DHID + t * 4);
#pragma unroll
      for (int r = 0; r < 16; ++r) {
        const float kv = ks_[r][ii];
        acc[r].x += kv * w.x; acc[r].y += kv * w.y;
        acc[r].z += kv * w.z; acc[r].w += kv * w.w;
      }
    }
  }
#pragma unroll
  for (int r = 0; r < 16; ++r)
    *reinterpret_cast<float4*>(kk + (long)(r0 + r) * DHID + t * 4) = acc[r];
}

// ---------------- Mb[b,v,h] = bf16((1/32) sum_k W_o[k,v]*kk[b,k,h]) --------
__global__ __launch_bounds__(256) void mb_kernel(
    const float* __restrict__ kk, const float* __restrict__ W_o,
    unsigned short* __restrict__ Mb) {
  const int bv = blockIdx.x;
  const int b = bv >> 9, v = bv & 511;
  const int t = threadIdx.x;
  const float* kb = kk + (long)b * LK * DHID + t * 4;
  float ax = 0.f, ay = 0.f, az = 0.f, aw = 0.f;
  for (int k = 0; k < LK; ++k) {
    const float wo = W_o[k * DVAL + v];
    const float4 kv = *reinterpret_cast<const float4*>(kb + (long)k * DHID);
    ax += wo * kv.x; ay += wo * kv.y; az += wo * kv.z; aw += wo * kv.w;
  }
  u16x4 r;
  r[0] = f2b(ax * 0.03125f); r[1] = f2b(ay * 0.03125f);
  r[2] = f2b(az * 0.03125f); r[3] = f2b(aw * 0.03125f);
  *reinterpret_cast<u16x4*>(Mb + (long)bv * DHID + t * 4) = r;
}

// ---------------- bf16 MFMA GEMM, both operands [rows, K] row-major --------
// C[m,n] = sum_k A[m*lda+k] * B[n*ldb+k]
#define BM 128
#define BN 128
#define BK 64
#define LDSK 72  // +8 bf16 pad: 16B-aligned rows, 2-way max bank aliasing

template <typename OT>
__global__ __launch_bounds__(256, 2) void gemm_bt_kernel(
    const unsigned short* __restrict__ Ag, const unsigned short* __restrict__ Bg,
    OT* __restrict__ Cg, int K, int lda, int ldb, int ldc,
    long sA, long sB, long sC) {
  __shared__ unsigned short As[BM * LDSK];
  __shared__ unsigned short Bs[BN * LDSK];

  const int tid = threadIdx.x;
  Ag += (long)blockIdx.z * sA;
  Bg += (long)blockIdx.z * sB;
  Cg += (long)blockIdx.z * sC;
  const int m0 = blockIdx.y * BM;
  const int n0 = blockIdx.x * BN;

  const int w    = tid >> 6;
  const int lane = tid & 63;
  const int l15  = lane & 15;
  const int quad = lane >> 4;
  const int wm   = (w >> 1) * 64;
  const int wn   = (w & 1) * 64;

  f32x4 acc[4][4];
#pragma unroll
  for (int i = 0; i < 4; ++i)
#pragma unroll
    for (int j = 0; j < 4; ++j) acc[i][j] = (f32x4)(0.0f);

  const int srow = tid >> 1;        // 128 rows, 2 threads/row
  const int sseg = (tid & 1) * 32;  // 32 bf16 each = 4 x 16B
  const unsigned short* apsrc = Ag + (long)(m0 + srow) * lda + sseg;
  const unsigned short* bpsrc = Bg + (long)(n0 + srow) * ldb + sseg;
  float4* adst = reinterpret_cast<float4*>(&As[srow * LDSK + sseg]);
  float4* bdst = reinterpret_cast<float4*>(&Bs[srow * LDSK + sseg]);

  for (int k0 = 0; k0 < K; k0 += BK) {
    const float4* as = reinterpret_cast<const float4*>(apsrc + k0);
    const float4* bs = reinterpret_cast<const float4*>(bpsrc + k0);
    const float4 a0 = as[0], a1 = as[1], a2 = as[2], a3 = as[3];
    const float4 b0 = bs[0], b1 = bs[1], b2 = bs[2], b3 = bs[3];
    adst[0] = a0; adst[1] = a1; adst[2] = a2; adst[3] = a3;
    bdst[0] = b0; bdst[1] = b1; bdst[2] = b2; bdst[3] = b3;
    __syncthreads();

#pragma unroll
    for (int ks = 0; ks < BK; ks += 32) {
      bf16x8 af[4], bfv[4];
#pragma unroll
      for (int i = 0; i < 4; ++i)
        af[i] = *reinterpret_cast<const bf16x8*>(&As[(wm + i * 16 + l15) * LDSK + ks + quad * 8]);
#pragma unroll
      for (int j = 0; j < 4; ++j)
        bfv[j] = *reinterpret_cast<const bf16x8*>(&Bs[(wn + j * 16 + l15) * LDSK + ks + quad * 8]);
#pragma unroll
      for (int i = 0; i < 4; ++i)
#pragma unroll
        for (int j = 0; j < 4; ++j)
          acc[i][j] = __builtin_amdgcn_mfma_f32_16x16x32_bf16(af[i], bfv[j], acc[i][j], 0, 0, 0);
    }
    __syncthreads();
  }

  // epilogue: D row = wm+i*16+quad*4+r, col = wn+j*16+l15
#pragma unroll
  for (int i = 0; i < 4; ++i) {
#pragma unroll
    for (int j = 0; j < 4; ++j) {
#pragma unroll
      for (int r = 0; r < 4; ++r) {
        const int row = m0 + wm + i * 16 + quad * 4 + r;
        const int col = n0 + wn + j * 16 + l15;
        const float val = acc[i][j][r];
        if constexpr (sizeof(OT) == 2) {
          reinterpret_cast<__hip_bfloat16*>(Cg)[(long)row * ldc + col] = __float2bfloat16(val);
        } else {
          reinterpret_cast<float*>(Cg)[(long)row * ldc + col] = val;
        }
      }
    }
  }
}

// ---------------- masked softmax over q; f32 in-place + bf16 copy ----------
__global__ __launch_bounds__(256) void softmax_kernel(
    float* __restrict__ attn, unsigned short* __restrict__ attnb,
    const int* __restrict__ vlens) {
  __shared__ float smax[4], ssum[4];
  const long base = (long)blockIdx.x * LQ;
  const int vl = vlens[blockIdx.x >> 9];
  const int t = threadIdx.x;
  float x[8];
  float mx = -3.0e38f;
#pragma unroll
  for (int u = 0; u < 8; ++u) {
    const int q = u * 256 + t;
    float v = attn[base + q];
    if (q >= vl) v = -1000000.0f;
    x[u] = v;
    mx = fmaxf(mx, v);
  }
#pragma unroll
  for (int off = 32; off > 0; off >>= 1) mx = fmaxf(mx, __shfl_down(mx, off));
  if ((t & 63) == 0) smax[t >> 6] = mx;
  __syncthreads();
  mx = fmaxf(fmaxf(smax[0], smax[1]), fmaxf(smax[2], smax[3]));
  float s = 0.f;
#pragma unroll
  for (int u = 0; u < 8; ++u) { x[u] = __expf(x[u] - mx); s += x[u]; }
#pragma unroll
  for (int off = 32; off > 0; off >>= 1) s += __shfl_down(s, off);
  if ((t & 63) == 0) ssum[t >> 6] = s;
  __syncthreads();
  s = ssum[0] + ssum[1] + ssum[2] + ssum[3];
  const float inv = 1.0f / s;
#pragma unroll
  for (int u = 0; u < 8; ++u) {
    const float v = x[u] * inv;
    attn[base + u * 256 + t] = v;
    attnb[base + u * 256 + t] = f2b(v);
  }
}

extern "C" void kernel_launch(void* const* d_in, const int* in_sizes, int n_in,
                              void* d_out, int out_size, void* d_ws, size_t ws_size,
                              hipStream_t stream) {
  const float* queries = (const float*)d_in[0];
  const float* keys    = (const float*)d_in[1];
  const float* values  = (const float*)d_in[2];
  const int*   vlens   = (const int*)d_in[3];
  const float* W_q     = (const float*)d_in[4];
  const float* W_k     = (const float*)d_in[5];
  const float* W_v     = (const float*)d_in[6];
  const float* W_o     = (const float*)d_in[7];

  float* out  = (float*)d_out;                       // [32][512][1024]
  float* attn = out + (size_t)NB * DVAL * DHID;      // [32][512][2048] f32

  // workspace layout (aliased by liveness; peak ~246 MB)
  char* ws = (char*)d_ws;
  unsigned short* qb    = (unsigned short*)(ws + 0);          // 134.2 MB; later vT
  unsigned short* vT    = qb;                                  // alias (qb dead after logits)
  unsigned short* Mbb   = (unsigned short*)(ws + 134217728UL); // 33.5 MB; later attnb (67 MB)
  unsigned short* attnb = Mbb;                                 // alias (Mbb dead after N GEMM)
  unsigned short* Nb    = (unsigned short*)(ws + 201326592UL); // 33.5 MB; later Tb
  unsigned short* Tb    = Nb;                                  // alias (Nb dead after logits)
  float*          kk    = (float*)(ws + 234881024UL);          // 6.55 MB
  unsigned short* wqb   = (unsigned short*)(ws + 241434624UL); // 2.1 MB
  unsigned short* wvT   = (unsigned short*)(ws + 243531776UL); // 2.1 MB

  // --- pre-pass conversions ---
  cvt_bf16_kernel<<<dim3(32768), 256, 0, stream>>>(queries, qb, (long)NB * LQ * DIN);
  cvt_bf16_kernel<<<dim3(512),   256, 0, stream>>>(W_q, wqb, (long)DIN * DHID);
  transpose_bf16_kernel<<<dim3(16, 16, 1), 256, 0, stream>>>(W_v, wvT, DIN, DHID, 0, 0);

  kproj_kernel<<<dim3(100), 256, 0, stream>>>(keys, W_k, kk);
  mb_kernel<<<dim3(NB * DVAL), 256, 0, stream>>>(kk, W_o, Mbb);

  // N[b] = Mb[b] @ W_q^T : M=512,N=1024,K=1024
  gemm_bt_kernel<__hip_bfloat16><<<dim3(8, 4, NB), 256, 0, stream>>>(
      Mbb, wqb, (__hip_bfloat16*)Nb, 1024, 1024, 1024, 1024,
      (long)512 * 1024, 0, (long)512 * 1024);

  // logits[b] = N[b] @ qb[b]^T : M=512,N=2048,K=1024 -> d_out attn region
  gemm_bt_kernel<float><<<dim3(16, 4, NB), 256, 0, stream>>>(
      Nb, qb, attn, 1024, 1024, 1024, 2048,
      (long)512 * 1024, (long)2048 * 1024, (long)512 * 2048);

  // vT[b] = bf16(values[b]^T) : [2048,1024] -> [1024,2048]  (qb now dead)
  transpose_bf16_kernel<<<dim3(16, 32, NB), 256, 0, stream>>>(
      values, vT, LQ, DIN, (long)LQ * DIN, (long)DIN * LQ);

  softmax_kernel<<<dim3(NB * DVAL), 256, 0, stream>>>(attn, attnb, vlens);

  // T[b] = attnb[b] @ values[b] : M=512,N=1024,K=2048
  gemm_bt_kernel<__hip_bfloat16><<<dim3(8, 4, NB), 256, 0, stream>>>(
      attnb, vT, (__hip_bfloat16*)Tb, 2048, 2048, 2048, 1024,
      (long)512 * 2048, (long)1024 * 2048, (long)512 * 1024);

  // out[b] = T[b] @ W_v : M=512,N=1024,K=1024
  gemm_bt_kernel<float><<<dim3(8, 4, NB), 256, 0, stream>>>(
      Tb, wvT, out, 1024, 1024, 1024, 1024,
      (long)512 * 1024, 0, (long)512 * 1024);
}